// Round 3
// baseline (492.781 us; speedup 1.0000x reference)
//
#include <hip/hip_runtime.h>
#include <hip/hip_bf16.h>
#include <hip/hip_fp16.h>

#define SEQ 1024
#define HEADS 16
#define HDIM 64
#define EMB 1024
#define TQ 32            // q rows per attention block (2 row-tiles)
#define KQ 256           // k per quarter (split-K/4, looped in-kernel)
#define PBA_S 264        // PbA row stride (u16): 256+8
#define PBB_S 328        // PbB row stride (u16): window<=303 + read slack -> 328
#define RELK_ROWS 1040   // 1025 real + zero pad
#define RELV_S 1064      // relv^T padded col stride (zeros past 1024)

typedef __bf16 bf16x8 __attribute__((ext_vector_type(8)));
typedef float floatx4 __attribute__((ext_vector_type(4)));
typedef unsigned short u16x4 __attribute__((ext_vector_type(4)));

#if __has_builtin(__builtin_amdgcn_exp2f)
#define EXP2F(x) __builtin_amdgcn_exp2f(x)
#else
#define EXP2F(x) exp2f(x)
#endif

// scores are pre-scaled by log2(e)/8 in the Q projection so softmax uses exp2
#define QSCALE 0.18033688011112042f

static __device__ __forceinline__ unsigned short f2bu(float f) {
    __bf16 h = (__bf16)f;
    return __builtin_bit_cast(unsigned short, h);
}
static __device__ __forceinline__ float b2f(unsigned short u) {
    unsigned v = ((unsigned)u) << 16;
    return __builtin_bit_cast(float, v);
}

// ---------------------------------------------------------------------------
// Kernel 1: fused projections + prep. grid (1024+1626, 3).
// bx < 1024: MFMA projection for slice `which` (q/k/v); per-head W is
//   converted f32->bf16 INLINE (no prep dependency). Q scaled by log2(e)/8.
// bx >= 1024: prep work (Wfc/relk/relv bf16 conversion + mask partial
//   reduction), spread over the 3 y-slices: gidx = (bx-1024) + which*1626
//   in [0, 4878). [0,4622): conversions; [4622,4878): mask chunks -> part.
// ---------------------------------------------------------------------------
#define NW (1024 * 1024)
#define NRK (RELK_ROWS * 64)
#define NRV (64 * RELV_S)
#define CONVB ((NW + NRK + NRV) / 256)   // = 4622 exactly
#define PREPY 1626                        // (4622 + 256) / 3 + rounding = 1626*3 = 4878
__global__ __launch_bounds__(256) void sa_projprep_kernel(
    const float* __restrict__ qin, const float* __restrict__ kin,
    const float* __restrict__ vin,
    const float* __restrict__ Wq, const float* __restrict__ Wk,
    const float* __restrict__ Wv,
    const float* __restrict__ bq, const float* __restrict__ bk,
    const float* __restrict__ bv_,
    const float* __restrict__ Wfc, const float* __restrict__ relk,
    const float* __restrict__ relv, const int* __restrict__ mask,
    unsigned short* __restrict__ qb, unsigned short* __restrict__ kb,
    unsigned short* __restrict__ vtb,
    unsigned short* __restrict__ wfcb, unsigned short* __restrict__ relkb,
    unsigned short* __restrict__ relvtb, unsigned* __restrict__ part) {
    __shared__ unsigned wok[4];
    const int t = threadIdx.x;
    const int which = blockIdx.y;
    const int bx = blockIdx.x;

    if (bx >= 1024) {
        const int gidx = (bx - 1024) + which * PREPY;
        if (gidx < CONVB) {
            int i = gidx * 256 + t;
            if (i < NW) {
                wfcb[i] = f2bu(Wfc[i]);
            } else if (i < NW + NRK) {
                int j = i - NW;
                int r = j >> 6, d = j & 63;
                relkb[j] = (r <= 1024) ? f2bu(relk[r * 64 + d]) : 0;
            } else {
                int j = i - NW - NRK;
                int d = j / RELV_S, c = j - d * RELV_S;
                relvtb[j] = (c <= 1024) ? f2bu(relv[c * 64 + d]) : 0;
            }
        } else if (gidx < CONVB + 256) {
            const int mb = gidx - CONVB;
            const int b = mb >> 6, chunk = mb & 63;
            const int4* p = (const int4*)(mask + (size_t)b * (SEQ * SEQ) + chunk * 16384);
            int ok = 1;
#pragma unroll
            for (int i = 0; i < 16; ++i) {
                int4 v = p[t + i * 256];
                ok &= (v.x != 0 && v.y != 0 && v.z != 0 && v.w != 0) ? 1 : 0;
            }
            unsigned long long bal = __ballot(ok);
            if ((t & 63) == 0) wok[t >> 6] = (bal == ~0ull) ? 1u : 0u;
            __syncthreads();
            if (t == 0)
                part[b * 64 + chunk] = (wok[0] & wok[1] & wok[2] & wok[3]) ? 0xFFFFFFFFu : 0u;
        }
        return;
    }

    const int w = t >> 6, lane = t & 63;
    const int quad = lane >> 4, l16 = lane & 15;
    const int r0 = (bx >> 2) * 16;
    const int h = (bx & 3) * 4 + w;
    const int bidx = r0 >> 10;
    const int l0 = r0 & 1023;
    const float* x = (which == 0) ? qin : (which == 1) ? kin : vin;
    const float* Wsrc = (which == 0) ? Wq : (which == 1) ? Wk : Wv;
    const float* bias = (which == 0) ? bq : (which == 1) ? bk : bv_;

    bf16x8 wf[4][2];
#pragma unroll
    for (int dt = 0; dt < 4; ++dt)
#pragma unroll
        for (int ks = 0; ks < 2; ++ks) {
            const float* wp = Wsrc + (size_t)(dt * 16 + l16) * 64 + ks * 32 + quad * 8;
            float4 lo = *(const float4*)wp;
            float4 hi = *(const float4*)(wp + 4);
            unsigned short pw[8];
            pw[0] = f2bu(lo.x); pw[1] = f2bu(lo.y); pw[2] = f2bu(lo.z); pw[3] = f2bu(lo.w);
            pw[4] = f2bu(hi.x); pw[5] = f2bu(hi.y); pw[6] = f2bu(hi.z); pw[7] = f2bu(hi.w);
            wf[dt][ks] = *(bf16x8*)pw;
        }

    bf16x8 xf[2];
#pragma unroll
    for (int ks = 0; ks < 2; ++ks) {
        const float* xp = x + (size_t)(r0 + l16) * EMB + h * 64 + ks * 32 + quad * 8;
        float4 lo = *(const float4*)xp;
        float4 hi = *(const float4*)(xp + 4);
        unsigned short px[8];
        px[0] = f2bu(lo.x); px[1] = f2bu(lo.y); px[2] = f2bu(lo.z); px[3] = f2bu(lo.w);
        px[4] = f2bu(hi.x); px[5] = f2bu(hi.y); px[6] = f2bu(hi.z); px[7] = f2bu(hi.w);
        xf[ks] = *(bf16x8*)px;
    }
    const int bh = bidx * HEADS + h;

    if (which < 2) {
        float biasd[4];
#pragma unroll
        for (int dt = 0; dt < 4; ++dt) biasd[dt] = bias[dt * 16 + l16];
        const float sc = (which == 0) ? QSCALE : 1.0f;
        unsigned short* dst = (which == 0) ? qb : kb;
        floatx4 acc[4];
#pragma unroll
        for (int dt = 0; dt < 4; ++dt) acc[dt] = floatx4{0.f, 0.f, 0.f, 0.f};
#pragma unroll
        for (int dt = 0; dt < 4; ++dt)
#pragma unroll
            for (int ks = 0; ks < 2; ++ks)
                acc[dt] = __builtin_amdgcn_mfma_f32_16x16x32_bf16(xf[ks], wf[dt][ks], acc[dt], 0, 0, 0);
#pragma unroll
        for (int dt = 0; dt < 4; ++dt)
#pragma unroll
            for (int i = 0; i < 4; ++i) {
                const int lr = l0 + quad * 4 + i;
                float val = (acc[dt][i] + biasd[dt]) * sc;
                dst[((size_t)bh * SEQ + lr) * 64 + dt * 16 + l16] = f2bu(val);
            }
    } else {
        float biasv[4][4];
#pragma unroll
        for (int dt = 0; dt < 4; ++dt)
#pragma unroll
            for (int i = 0; i < 4; ++i) biasv[dt][i] = bias[dt * 16 + quad * 4 + i];
        floatx4 acc[4];
#pragma unroll
        for (int dt = 0; dt < 4; ++dt) acc[dt] = floatx4{0.f, 0.f, 0.f, 0.f};
        // v transposed: A = Wv rows (d), B = X rows (l) -> C[d][l]
#pragma unroll
        for (int dt = 0; dt < 4; ++dt)
#pragma unroll
            for (int ks = 0; ks < 2; ++ks)
                acc[dt] = __builtin_amdgcn_mfma_f32_16x16x32_bf16(wf[dt][ks], xf[ks], acc[dt], 0, 0, 0);
#pragma unroll
        for (int dt = 0; dt < 4; ++dt)
#pragma unroll
            for (int i = 0; i < 4; ++i) {
                const int d = dt * 16 + quad * 4 + i;
                float val = acc[dt][i] + biasv[dt][i];
                vtb[((size_t)bh * 64 + d) * SEQ + l0 + l16] = f2bu(val);
            }
    }
}

// ---------------------------------------------------------------------------
// Kernel 2: fully-fused attention (no-max softmax, validated round 2).
// 2048 blocks (bh x 32 qtiles), 512 thr (8 waves), loop over 4 k-quarters.
// SPILL FIX vs round 2: pk is never held across barriers -- Phase C stores
// P to PbA immediately; the skewed PbB store reloads its own u16x4s from
// PbA after the zero-fill barrier. K-fragments are loaded once per quarter
// and S-accumulators live per row-tile only. Mask flags are folded from
// `part` by wave 0 at kernel start (maskred kernel deleted).
// Peak VGPR ~75 -> fits __launch_bounds__(512,6) = 3 blocks/CU.
// ---------------------------------------------------------------------------
__global__ __launch_bounds__(512, 6) void sa_attn_kernel(
    const unsigned short* __restrict__ qb, const unsigned short* __restrict__ kb,
    const unsigned short* __restrict__ vtb, const int* __restrict__ mask,
    const unsigned short* __restrict__ relkb, const unsigned short* __restrict__ relvtb,
    const unsigned* __restrict__ part, unsigned short* __restrict__ aob) {
    __shared__ __align__(16) unsigned short PbA[TQ * PBA_S];  // 16896 B, P in k-layout
    __shared__ __align__(16) unsigned short PbB[TQ * PBB_S];  // 20992 B, RS then P in c-layout
    __shared__ unsigned sflag;

    const int tid = threadIdx.x;
    const int w = tid >> 6, lane = tid & 63;
    const int quad = lane >> 4, l16 = lane & 15;
    const int bid = blockIdx.x;
    const int qt = bid & 31;
    const int bh = bid >> 5;
    const int q0 = qt * TQ;
    const int b = bh >> 4, h = bh & 15;

    // fold mask partials (b = bid>>9); wave 0 only
    if (tid < 64) {
        unsigned f = part[(bid >> 9) * 64 + tid];
        unsigned long long bal = __ballot(f != 0u);
        if (tid == 0) sflag = (bal == ~0ull) ? 1u : 0u;
    }

    // Q B-fragments for BOTH row-tiles (lane l16 = q row within tile)
    bf16x8 aq[2][2];
#pragma unroll
    for (int rt = 0; rt < 2; ++rt) {
        const unsigned short* qrow = qb + ((size_t)bh * SEQ + q0 + rt * 16 + l16) * 64;
        aq[rt][0] = *(const bf16x8*)(qrow + quad * 8);
        aq[rt][1] = *(const bf16x8*)(qrow + 32 + quad * 8);
    }

    // Phase-F wave identity: wave (rtF, dq) owns row-tile rtF, d-block dq.
    const int rtF = w & 1;
    const int dq = w >> 1;
    const unsigned short* vrow = vtb + ((size_t)bh * 64 + dq * 16 + l16) * SEQ;
    const unsigned short* rbase = relvtb + (size_t)(dq * 16 + l16) * RELV_S;
    const float rv0 = b2f(rbase[0]);      // relv[0][d]
    const float rv1 = b2f(rbase[1024]);   // relv[1024][d]
    unsigned short ob[8];
#pragma unroll
    for (int j = 0; j < 8; ++j) ob[j] = 0x3F80;   // bf16 1.0
    const bf16x8 onesf = *(bf16x8*)ob;

    // persistent accumulators (no rescale needed without max subtraction)
    floatx4 OaccA = {0.f, 0.f, 0.f, 0.f};   // P@V
    floatx4 OaccB = {0.f, 0.f, 0.f, 0.f};   // P_c@relv (interior)
    floatx4 dnm = {0.f, 0.f, 0.f, 0.f};     // sum P (total)
    floatx4 tl = {0.f, 0.f, 0.f, 0.f};      // low-clip tail mass
    floatx4 th = {0.f, 0.f, 0.f, 0.f};      // high-clip tail mass

    __syncthreads();   // sflag ready
    const bool mfull = (sflag != 0u);
    const int kc = w;  // 32-col k chunk owned in phases C/D

    for (int qu = 0; qu < 4; ++qu) {
        const int k0 = qu * KQ;
        const bool clipped = (k0 - (q0 + 31) < -512) || (k0 + 255 - q0 > 512);
        const int cmin = min(512, max(-512, k0 - (q0 + 31))) + 512;
        const int cmax = min(512, max(-512, k0 + 255 - q0)) + 512;
        const int BASE = cmin & ~15;   // unified RS/P/relv column base (16-aligned)

        if (qu) __syncthreads();   // (A) prev-quarter Phase-F reads done

        // ---- Phase B: RS^T = mfma(relk, Q) over window -> PbB[q][c-BASE] ----
        {
            const int ct_lo = cmin >> 4, ct_hi = cmax >> 4;
            for (int ct = ct_lo + w; ct <= ct_hi; ct += 8) {
                bf16x8 bf0 = *(const bf16x8*)(relkb + (size_t)(ct * 16 + l16) * 64 + quad * 8);
                bf16x8 bf1 = *(const bf16x8*)(relkb + (size_t)(ct * 16 + l16) * 64 + 32 + quad * 8);
                floatx4 r0 = {0.f, 0.f, 0.f, 0.f}, r1 = {0.f, 0.f, 0.f, 0.f};
                r0 = __builtin_amdgcn_mfma_f32_16x16x32_bf16(bf0, aq[0][0], r0, 0, 0, 0);
                r0 = __builtin_amdgcn_mfma_f32_16x16x32_bf16(bf1, aq[0][1], r0, 0, 0, 0);
                r1 = __builtin_amdgcn_mfma_f32_16x16x32_bf16(bf0, aq[1][0], r1, 0, 0, 0);
                r1 = __builtin_amdgcn_mfma_f32_16x16x32_bf16(bf1, aq[1][1], r1, 0, 0, 0);
                const int co = ct * 16 + quad * 4 - BASE;   // >=0, mult of 4
                u16x4 p0, p1;
#pragma unroll
                for (int i = 0; i < 4; ++i) { p0[i] = f2bu(r0[i]); p1[i] = f2bu(r1[i]); }
                *(u16x4*)&PbB[(size_t)l16 * PBB_S + co] = p0;
                *(u16x4*)&PbB[(size_t)(16 + l16) * PBB_S + co] = p1;
            }
        }
        __syncthreads();   // (B)

        // ---- Phase C: S^T = mfma(K, Q) per row-tile; gather RS; exp2 ->
        // pack -> PbA store (values die immediately, no cross-barrier regs) ----
        bf16x8 kf[2][2];
#pragma unroll
        for (int tt = 0; tt < 2; ++tt) {
            const unsigned short* krow = kb + ((size_t)bh * SEQ + k0 + kc * 32 + tt * 16 + l16) * 64;
            kf[tt][0] = *(const bf16x8*)(krow + quad * 8);
            kf[tt][1] = *(const bf16x8*)(krow + 32 + quad * 8);
        }
#pragma unroll
        for (int rt = 0; rt < 2; ++rt) {
            floatx4 a0 = {0.f, 0.f, 0.f, 0.f}, a1 = {0.f, 0.f, 0.f, 0.f};
            a0 = __builtin_amdgcn_mfma_f32_16x16x32_bf16(kf[0][0], aq[rt][0], a0, 0, 0, 0);
            a0 = __builtin_amdgcn_mfma_f32_16x16x32_bf16(kf[0][1], aq[rt][1], a0, 0, 0, 0);
            a1 = __builtin_amdgcn_mfma_f32_16x16x32_bf16(kf[1][0], aq[rt][0], a1, 0, 0, 0);
            a1 = __builtin_amdgcn_mfma_f32_16x16x32_bf16(kf[1][1], aq[rt][1], a1, 0, 0, 0);
            const unsigned short* rsrow = &PbB[(size_t)(rt * 16 + l16) * PBB_S];
            const int q = q0 + rt * 16 + l16;
            const int cb = k0 + kc * 32 - q + 512;
            u16x4 pa0, pa1;
            if (mfull) {
                if (!clipped) {
#pragma unroll
                    for (int i = 0; i < 4; ++i) {
                        pa0[i] = f2bu(EXP2F(a0[i] + b2f(rsrow[cb + quad * 4 + i - BASE])));
                        pa1[i] = f2bu(EXP2F(a1[i] + b2f(rsrow[cb + 16 + quad * 4 + i - BASE])));
                    }
                } else {
#pragma unroll
                    for (int i = 0; i < 4; ++i) {
                        const int c0 = cb + quad * 4 + i;
                        const int c1 = c0 + 16;
                        const int r0i = min(1024, max(0, c0));
                        const int r1i = min(1024, max(0, c1));
                        pa0[i] = f2bu(EXP2F(a0[i] + b2f(rsrow[r0i - BASE])));
                        pa1[i] = f2bu(EXP2F(a1[i] + b2f(rsrow[r1i - BASE])));
                    }
                }
            } else {
                const int* mrow = mask + (size_t)b * (SEQ * SEQ) + (size_t)q * SEQ;
#pragma unroll
                for (int i = 0; i < 4; ++i) {
                    const int k0i = k0 + kc * 32 + quad * 4 + i;
                    const int k1i = k0i + 16;
                    const int c0 = cb + quad * 4 + i;
                    const int c1 = c0 + 16;
                    const int r0i = min(1024, max(0, c0));
                    const int r1i = min(1024, max(0, c1));
                    float s0 = a0[i] + b2f(rsrow[r0i - BASE]);
                    float s1 = a1[i] + b2f(rsrow[r1i - BASE]);
                    s0 = (mrow[k0i] == 0) ? -1e20f : s0;
                    s1 = (mrow[k1i] == 0) ? -1e20f : s1;
                    pa0[i] = f2bu(EXP2F(s0));
                    pa1[i] = f2bu(EXP2F(s1));
                }
            }
            unsigned short* parow = &PbA[(size_t)(rt * 16 + l16) * PBA_S + kc * 32];
            *(u16x4*)(parow + quad * 4) = pa0;
            *(u16x4*)(parow + 16 + quad * 4) = pa1;
        }
        __syncthreads();   // (C) all RS gathers done -> PbB reusable

        // ---- zero-fill PbB ----
        for (int g = tid; g < TQ * (PBB_S / 8); g += 512) {
            int row = g / (PBB_S / 8), j = g - row * (PBB_S / 8);
            *(uint4*)&PbB[row * PBB_S + j * 8] = make_uint4(0u, 0u, 0u, 0u);
        }
        __syncthreads();   // (D)

        // ---- PbB store: reload own P from PbA, store skewed c-layout ----
#pragma unroll
        for (int rt = 0; rt < 2; ++rt) {
            unsigned short* pbrow = &PbB[(size_t)(rt * 16 + l16) * PBB_S];
            const unsigned short* parow = &PbA[(size_t)(rt * 16 + l16) * PBA_S + kc * 32];
            const int cbase = k0 + kc * 32 - (q0 + rt * 16 + l16) + 512;
#pragma unroll
            for (int tt = 0; tt < 2; ++tt) {
                u16x4 pr = *(const u16x4*)(parow + tt * 16 + quad * 4);
                const int c0 = cbase + tt * 16 + quad * 4;
                if (!clipped) {
#pragma unroll
                    for (int i = 0; i < 4; ++i) pbrow[c0 + i - BASE] = pr[i];
                } else {
#pragma unroll
                    for (int i = 0; i < 4; ++i) {
                        const int c = c0 + i;
                        if ((unsigned)(c - 1) < 1023u) pbrow[c - BASE] = pr[i];
                    }
                }
            }
        }
        __syncthreads();   // (E)

        // ---- Phase F: accumulate O, denom, tails for this quarter ----
        {
            floatx4 accS = {0.f, 0.f, 0.f, 0.f};
            floatx4 accSI = {0.f, 0.f, 0.f, 0.f};
#pragma unroll
            for (int it = 0; it < 8; ++it) {
                const int co = it * 32 + quad * 8;
                bf16x8 ap = *(const bf16x8*)&PbA[(size_t)(rtF * 16 + l16) * PBA_S + co];
                bf16x8 bv = *(const bf16x8*)(vrow + k0 + co);
                OaccA = __builtin_amdgcn_mfma_f32_16x16x32_bf16(ap, bv, OaccA, 0, 0, 0);
                accS = __builtin_amdgcn_mfma_f32_16x16x32_bf16(ap, onesf, accS, 0, 0, 0);
            }
            const int nksB = ((cmax - BASE) >> 5) + 1;
            for (int ks = 0; ks < nksB; ++ks) {
                const int co = ks * 32 + quad * 8;
                bf16x8 ar = *(const bf16x8*)&PbB[(size_t)(rtF * 16 + l16) * PBB_S + co];
                bf16x8 br = *(const bf16x8*)(rbase + BASE + co);
                OaccB = __builtin_amdgcn_mfma_f32_16x16x32_bf16(ar, br, OaccB, 0, 0, 0);
                accSI = __builtin_amdgcn_mfma_f32_16x16x32_bf16(ar, onesf, accSI, 0, 0, 0);
            }
#pragma unroll
            for (int i = 0; i < 4; ++i) {
                dnm[i] += accS[i];
                const float tail = accS[i] - accSI[i];
                const int qi = q0 + rtF * 16 + quad * 4 + i;
                if (qi >= k0 + 512) tl[i] += tail;
                if (qi <= k0 - 257) th[i] += tail;
            }
        }
    }

    // ---- epilogue: normalize and write aob directly ----
#pragma unroll
    for (int i = 0; i < 4; ++i) {
        const int row = rtF * 16 + quad * 4 + i;
        const int q = q0 + row;
        const float val = (OaccA[i] + OaccB[i] + tl[i] * rv0 + th[i] * rv1) / dnm[i];
        aob[((size_t)b * SEQ + q) * EMB + h * 64 + dq * 16 + l16] = f2bu(val);
    }
}

// ---------------------------------------------------------------------------
// Kernel 3: FC MFMA GEMM (unchanged). out = aob @ Wfc_b^T + bfc.
// ---------------------------------------------------------------------------
__global__ __launch_bounds__(256, 2) void sa_fc_kernel(
    const unsigned short* __restrict__ A, const unsigned short* __restrict__ W,
    const float* __restrict__ bias, float* __restrict__ out) {
    const int t = threadIdx.x;
    const int w = t >> 6, lane = t & 63;
    const int quad = lane >> 4, l16 = lane & 15;
    const int mw = blockIdx.x * 64 + (w & 1) * 32;
    const int nw = blockIdx.y * 256 + (w >> 1) * 128;

    floatx4 acc[2][8];
#pragma unroll
    for (int mt = 0; mt < 2; ++mt)
#pragma unroll
        for (int j = 0; j < 8; ++j) acc[mt][j] = floatx4{0.f, 0.f, 0.f, 0.f};
    float bj[8];
#pragma unroll
    for (int j = 0; j < 8; ++j) bj[j] = bias[nw + j * 16 + l16];

    for (int ks = 0; ks < 32; ++ks) {
        const int co = ks * 32 + quad * 8;
        bf16x8 af0 = *(const bf16x8*)(A + (size_t)(mw + l16) * EMB + co);
        bf16x8 af1 = *(const bf16x8*)(A + (size_t)(mw + 16 + l16) * EMB + co);
#pragma unroll
        for (int j = 0; j < 8; ++j) {
            bf16x8 bf = *(const bf16x8*)(W + (size_t)(nw + j * 16 + l16) * EMB + co);
            acc[0][j] = __builtin_amdgcn_mfma_f32_16x16x32_bf16(af0, bf, acc[0][j], 0, 0, 0);
            acc[1][j] = __builtin_amdgcn_mfma_f32_16x16x32_bf16(af1, bf, acc[1][j], 0, 0, 0);
        }
    }
#pragma unroll
    for (int mt = 0; mt < 2; ++mt)
#pragma unroll
        for (int j = 0; j < 8; ++j) {
            const int col = nw + j * 16 + l16;
#pragma unroll
            for (int i = 0; i < 4; ++i) {
                const size_t row = mw + mt * 16 + quad * 4 + i;
                out[row * EMB + col] = acc[mt][j][i] + bj[j];
            }
        }
}

extern "C" void kernel_launch(void* const* d_in, const int* in_sizes, int n_in,
                              void* d_out, int out_size, void* d_ws, size_t ws_size,
                              hipStream_t stream) {
    const float* query = (const float*)d_in[0];
    const float* key = (const float*)d_in[1];
    const float* value = (const float*)d_in[2];
    const int* mask = (const int*)d_in[3];
    const float* Wq = (const float*)d_in[4];
    const float* bq = (const float*)d_in[5];
    const float* Wk = (const float*)d_in[6];
    const float* bk = (const float*)d_in[7];
    const float* Wv = (const float*)d_in[8];
    const float* bv = (const float*)d_in[9];
    const float* Wfc = (const float*)d_in[10];
    const float* bfc = (const float*)d_in[11];
    const float* relk = (const float*)d_in[12];
    const float* relv = (const float*)d_in[13];
    float* out = (float*)d_out;

    char* base = (char*)d_ws;
    const size_t MB = (size_t)1 << 20;
    unsigned short* qb = (unsigned short*)(base + 0 * MB);        // 8 MB
    unsigned short* kb = (unsigned short*)(base + 8 * MB);        // 8 MB
    unsigned short* vtb = (unsigned short*)(base + 16 * MB);      // 8 MB
    unsigned short* wfcb = (unsigned short*)(base + 24 * MB);     // 2 MB
    unsigned short* relkb = (unsigned short*)(base + 26 * MB);                 // 133,120 B
    unsigned short* relvtb = (unsigned short*)(base + 26 * MB + 163840);       // 136,192 B
    unsigned* part = (unsigned*)(base + 26 * MB + 327680);                     // 1 KB
    unsigned short* aob = (unsigned short*)(base + 29 * MB);                   // 8 MB

    // single fused proj+prep launch; attn folds `part` itself; fc last.
    sa_projprep_kernel<<<dim3(1024 + PREPY, 3), 256, 0, stream>>>(
        query, key, value, Wq, Wk, Wv, bq, bk, bv,
        Wfc, relk, relv, mask, qb, kb, vtb, wfcb, relkb, relvtb, part);
    sa_attn_kernel<<<64 * 32, 512, 0, stream>>>(
        qb, kb, vtb, mask, relkb, relvtb, part, aob);
    sa_fc_kernel<<<dim3(64, 4), 256, 0, stream>>>(aob, wfcb, bfc, out);
}

// Round 4
// 400.564 us; speedup vs baseline: 1.2302x; 1.2302x over previous
//
#include <hip/hip_runtime.h>
#include <hip/hip_bf16.h>
#include <hip/hip_fp16.h>

#define SEQ 1024
#define HEADS 16
#define HDIM 64
#define EMB 1024
#define TQ 32            // q rows per attention block (2 row-tiles)
#define KQ 256           // k per quarter (split-K/4)
#define PBA_S 264        // PbA row stride (u16): 256+8
#define PBB_S 328        // PbB row stride (u16): window<=303 + read slack -> 328
#define RELK_ROWS 1040   // 1025 real + zero pad
#define RELV_S 1064      // relv^T padded col stride (zeros past 1024)

typedef __bf16 bf16x8 __attribute__((ext_vector_type(8)));
typedef float floatx4 __attribute__((ext_vector_type(4)));
typedef unsigned short u16x4 __attribute__((ext_vector_type(4)));

#if __has_builtin(__builtin_amdgcn_exp2f)
#define EXP2F(x) __builtin_amdgcn_exp2f(x)
#else
#define EXP2F(x) exp2f(x)
#endif

// scores are pre-scaled by log2(e)/8 in the Q projection so softmax uses exp2.
// P is computed as 2^(s-6): the constant 2^-6 keeps unnormalized half Opart
// far from overflow and cancels in the final O/denominator division.
#define QSCALE 0.18033688011112042f
#define PBIAS 6.0f

static __device__ __forceinline__ unsigned short f2bu(float f) {
    __bf16 h = (__bf16)f;
    return __builtin_bit_cast(unsigned short, h);
}
static __device__ __forceinline__ float b2f(unsigned short u) {
    unsigned v = ((unsigned)u) << 16;
    return __builtin_bit_cast(float, v);
}

// ---------------------------------------------------------------------------
// Kernel 1: fused projections + prep. grid (1024+1626, 3).
// bx < 1024: MFMA projection for slice `which` (q/k/v); per-head W converted
//   f32->bf16 inline. Q scaled by log2(e)/8.
// bx >= 1024: prep (Wfc/relk/relv bf16 conversion + mask partial reduction),
//   spread over the 3 y-slices.
// ---------------------------------------------------------------------------
#define NW (1024 * 1024)
#define NRK (RELK_ROWS * 64)
#define NRV (64 * RELV_S)
#define CONVB ((NW + NRK + NRV) / 256)   // = 4622 exactly
#define PREPY 1626                        // 3*1626 = 4878 = 4622 + 256
__global__ __launch_bounds__(256) void sa_projprep_kernel(
    const float* __restrict__ qin, const float* __restrict__ kin,
    const float* __restrict__ vin,
    const float* __restrict__ Wq, const float* __restrict__ Wk,
    const float* __restrict__ Wv,
    const float* __restrict__ bq, const float* __restrict__ bk,
    const float* __restrict__ bv_,
    const float* __restrict__ Wfc, const float* __restrict__ relk,
    const float* __restrict__ relv, const int* __restrict__ mask,
    unsigned short* __restrict__ qb, unsigned short* __restrict__ kb,
    unsigned short* __restrict__ vtb,
    unsigned short* __restrict__ wfcb, unsigned short* __restrict__ relkb,
    unsigned short* __restrict__ relvtb, unsigned* __restrict__ part) {
    __shared__ unsigned wok[4];
    const int t = threadIdx.x;
    const int which = blockIdx.y;
    const int bx = blockIdx.x;

    if (bx >= 1024) {
        const int gidx = (bx - 1024) + which * PREPY;
        if (gidx < CONVB) {
            int i = gidx * 256 + t;
            if (i < NW) {
                wfcb[i] = f2bu(Wfc[i]);
            } else if (i < NW + NRK) {
                int j = i - NW;
                int r = j >> 6, d = j & 63;
                relkb[j] = (r <= 1024) ? f2bu(relk[r * 64 + d]) : 0;
            } else {
                int j = i - NW - NRK;
                int d = j / RELV_S, c = j - d * RELV_S;
                relvtb[j] = (c <= 1024) ? f2bu(relv[c * 64 + d]) : 0;
            }
        } else if (gidx < CONVB + 256) {
            const int mb = gidx - CONVB;
            const int b = mb >> 6, chunk = mb & 63;
            const int4* p = (const int4*)(mask + (size_t)b * (SEQ * SEQ) + chunk * 16384);
            int ok = 1;
#pragma unroll
            for (int i = 0; i < 16; ++i) {
                int4 v = p[t + i * 256];
                ok &= (v.x != 0 && v.y != 0 && v.z != 0 && v.w != 0) ? 1 : 0;
            }
            unsigned long long bal = __ballot(ok);
            if ((t & 63) == 0) wok[t >> 6] = (bal == ~0ull) ? 1u : 0u;
            __syncthreads();
            if (t == 0)
                part[b * 64 + chunk] = (wok[0] & wok[1] & wok[2] & wok[3]) ? 0xFFFFFFFFu : 0u;
        }
        return;
    }

    const int w = t >> 6, lane = t & 63;
    const int quad = lane >> 4, l16 = lane & 15;
    const int r0 = (bx >> 2) * 16;
    const int h = (bx & 3) * 4 + w;
    const int bidx = r0 >> 10;
    const int l0 = r0 & 1023;
    const float* x = (which == 0) ? qin : (which == 1) ? kin : vin;
    const float* Wsrc = (which == 0) ? Wq : (which == 1) ? Wk : Wv;
    const float* bias = (which == 0) ? bq : (which == 1) ? bk : bv_;

    bf16x8 wf[4][2];
#pragma unroll
    for (int dt = 0; dt < 4; ++dt)
#pragma unroll
        for (int ks = 0; ks < 2; ++ks) {
            const float* wp = Wsrc + (size_t)(dt * 16 + l16) * 64 + ks * 32 + quad * 8;
            float4 lo = *(const float4*)wp;
            float4 hi = *(const float4*)(wp + 4);
            unsigned short pw[8];
            pw[0] = f2bu(lo.x); pw[1] = f2bu(lo.y); pw[2] = f2bu(lo.z); pw[3] = f2bu(lo.w);
            pw[4] = f2bu(hi.x); pw[5] = f2bu(hi.y); pw[6] = f2bu(hi.z); pw[7] = f2bu(hi.w);
            wf[dt][ks] = *(bf16x8*)pw;
        }

    bf16x8 xf[2];
#pragma unroll
    for (int ks = 0; ks < 2; ++ks) {
        const float* xp = x + (size_t)(r0 + l16) * EMB + h * 64 + ks * 32 + quad * 8;
        float4 lo = *(const float4*)xp;
        float4 hi = *(const float4*)(xp + 4);
        unsigned short px[8];
        px[0] = f2bu(lo.x); px[1] = f2bu(lo.y); px[2] = f2bu(lo.z); px[3] = f2bu(lo.w);
        px[4] = f2bu(hi.x); px[5] = f2bu(hi.y); px[6] = f2bu(hi.z); px[7] = f2bu(hi.w);
        xf[ks] = *(bf16x8*)px;
    }
    const int bh = bidx * HEADS + h;

    if (which < 2) {
        float biasd[4];
#pragma unroll
        for (int dt = 0; dt < 4; ++dt) biasd[dt] = bias[dt * 16 + l16];
        const float sc = (which == 0) ? QSCALE : 1.0f;
        unsigned short* dst = (which == 0) ? qb : kb;
        floatx4 acc[4];
#pragma unroll
        for (int dt = 0; dt < 4; ++dt) acc[dt] = floatx4{0.f, 0.f, 0.f, 0.f};
#pragma unroll
        for (int dt = 0; dt < 4; ++dt)
#pragma unroll
            for (int ks = 0; ks < 2; ++ks)
                acc[dt] = __builtin_amdgcn_mfma_f32_16x16x32_bf16(xf[ks], wf[dt][ks], acc[dt], 0, 0, 0);
#pragma unroll
        for (int dt = 0; dt < 4; ++dt)
#pragma unroll
            for (int i = 0; i < 4; ++i) {
                const int lr = l0 + quad * 4 + i;
                float val = (acc[dt][i] + biasd[dt]) * sc;
                dst[((size_t)bh * SEQ + lr) * 64 + dt * 16 + l16] = f2bu(val);
            }
    } else {
        float biasv[4][4];
#pragma unroll
        for (int dt = 0; dt < 4; ++dt)
#pragma unroll
            for (int i = 0; i < 4; ++i) biasv[dt][i] = bias[dt * 16 + quad * 4 + i];
        floatx4 acc[4];
#pragma unroll
        for (int dt = 0; dt < 4; ++dt) acc[dt] = floatx4{0.f, 0.f, 0.f, 0.f};
        // v transposed: A = Wv rows (d), B = X rows (l) -> C[d][l]
#pragma unroll
        for (int dt = 0; dt < 4; ++dt)
#pragma unroll
            for (int ks = 0; ks < 2; ++ks)
                acc[dt] = __builtin_amdgcn_mfma_f32_16x16x32_bf16(wf[dt][ks], xf[ks], acc[dt], 0, 0, 0);
#pragma unroll
        for (int dt = 0; dt < 4; ++dt)
#pragma unroll
            for (int i = 0; i < 4; ++i) {
                const int d = dt * 16 + quad * 4 + i;
                float val = acc[dt][i] + biasv[dt][i];
                vtb[((size_t)bh * 64 + d) * SEQ + l0 + l16] = f2bu(val);
            }
    }
}

// ---------------------------------------------------------------------------
// Kernel 2: quarter-K MFMA attention (split structure from round 1 -- 8192
// blocks (bh x 32 qtiles x 4 quarters), 512 thr -- the config measured at
// 199 us / 33.7 MB FETCH / 76% occupancy), with the validated no-max softmax:
// P = 2^(s - 6) absolute (no row max, no rescale). Removes rmax shuffles,
// mxpart/mxS LDS traffic, the finalize pass and one barrier. Unnormalized
// Opart (half, 2^-6-scaled so |O| << 65504) + per-quarter denom (float ms);
// combine divides by the summed denominators (2^-6 cancels).
// Mask flags folded from `part` by wave 0 (no separate maskred kernel).
// 4 barriers/block. LDS ~37.9 KB -> 4 blocks/CU.
// ---------------------------------------------------------------------------
__global__ __launch_bounds__(512, 8) void sa_attn_kernel(
    const unsigned short* __restrict__ qb, const unsigned short* __restrict__ kb,
    const unsigned short* __restrict__ vtb, const int* __restrict__ mask,
    const unsigned short* __restrict__ relkb, const unsigned short* __restrict__ relvtb,
    const unsigned* __restrict__ part, __half* __restrict__ Opart,
    float* __restrict__ ms) {
    __shared__ __align__(16) unsigned short PbA[TQ * PBA_S];  // 16896 B, P in k-layout
    __shared__ __align__(16) unsigned short PbB[TQ * PBB_S];  // 20992 B, RS then P in c-layout
    __shared__ unsigned sflag;

    const int tid = threadIdx.x;
    const int w = tid >> 6, lane = tid & 63;
    const int quad = lane >> 4, l16 = lane & 15;
    const int bid = blockIdx.x;
    const int quarter = bid & 3;
    const int qt = (bid >> 2) & 31;
    const int bh = bid >> 7;
    const int q0 = qt * TQ;
    const int k0 = quarter * KQ;
    const int b = bh >> 4;

    // fold mask partials for batch b; visible after barrier (1)
    if (tid < 64) {
        unsigned f = part[b * 64 + tid];
        unsigned long long bal = __ballot(f != 0u);
        if (tid == 0) sflag = (bal == ~0ull) ? 1u : 0u;
    }

    // block clips only if some |k-q| > 512
    const bool clipped = (k0 - (q0 + 31) < -512) || (k0 + 255 - q0 > 512);
    // c-window: c = clip(k-q,±512)+512
    const int cmin = min(512, max(-512, k0 - (q0 + 31))) + 512;
    const int cmax = min(512, max(-512, k0 + 255 - q0)) + 512;
    const int rsb = cmin & ~15;   // RS storage base (16-aligned)
    const int cb0 = cmin & ~7;    // PbB P-storage base (16B-aligned)

    // Q B-fragments for BOTH row-tiles (lane l16 = q row within tile)
    bf16x8 aq[2][2];
#pragma unroll
    for (int rt = 0; rt < 2; ++rt) {
        const unsigned short* qrow = qb + ((size_t)bh * SEQ + q0 + rt * 16 + l16) * 64;
        aq[rt][0] = *(const bf16x8*)(qrow + quad * 8);
        aq[rt][1] = *(const bf16x8*)(qrow + 32 + quad * 8);
    }

    // ---- Phase B: RS^T = mfma(relk, Q) over window -> PbB[q][c-rsb] ----
    {
        const int ct_lo = cmin >> 4, ct_hi = cmax >> 4;
        for (int ct = ct_lo + w; ct <= ct_hi; ct += 8) {
            bf16x8 bf0 = *(const bf16x8*)(relkb + (size_t)(ct * 16 + l16) * 64 + quad * 8);
            bf16x8 bf1 = *(const bf16x8*)(relkb + (size_t)(ct * 16 + l16) * 64 + 32 + quad * 8);
            floatx4 r0 = {0.f, 0.f, 0.f, 0.f}, r1 = {0.f, 0.f, 0.f, 0.f};
            r0 = __builtin_amdgcn_mfma_f32_16x16x32_bf16(bf0, aq[0][0], r0, 0, 0, 0);
            r0 = __builtin_amdgcn_mfma_f32_16x16x32_bf16(bf1, aq[0][1], r0, 0, 0, 0);
            r1 = __builtin_amdgcn_mfma_f32_16x16x32_bf16(bf0, aq[1][0], r1, 0, 0, 0);
            r1 = __builtin_amdgcn_mfma_f32_16x16x32_bf16(bf1, aq[1][1], r1, 0, 0, 0);
            const int co = ct * 16 + quad * 4 - rsb;   // >=0, mult of 4
            u16x4 p0, p1;
#pragma unroll
            for (int i = 0; i < 4; ++i) { p0[i] = f2bu(r0[i]); p1[i] = f2bu(r1[i]); }
            *(u16x4*)&PbB[(size_t)l16 * PBB_S + co] = p0;
            *(u16x4*)&PbB[(size_t)(16 + l16) * PBB_S + co] = p1;
        }
    }
    __syncthreads();   // (1)
    const bool mfull = (sflag != 0u);

    // ---- Phase C: S^T = mfma(K, Q) + RS gather into acc (no max, no mask) ----
    const int kc = w;               // 32-col k chunk
    floatx4 acc[2][2];              // [rt][tt]
#pragma unroll
    for (int rt = 0; rt < 2; ++rt)
#pragma unroll
        for (int tt = 0; tt < 2; ++tt) acc[rt][tt] = floatx4{0.f, 0.f, 0.f, 0.f};
#pragma unroll
    for (int tt = 0; tt < 2; ++tt) {
        const unsigned short* krow = kb + ((size_t)bh * SEQ + k0 + kc * 32 + tt * 16 + l16) * 64;
        bf16x8 kf0 = *(const bf16x8*)(krow + quad * 8);
        bf16x8 kf1 = *(const bf16x8*)(krow + 32 + quad * 8);
        acc[0][tt] = __builtin_amdgcn_mfma_f32_16x16x32_bf16(kf0, aq[0][0], acc[0][tt], 0, 0, 0);
        acc[0][tt] = __builtin_amdgcn_mfma_f32_16x16x32_bf16(kf1, aq[0][1], acc[0][tt], 0, 0, 0);
        acc[1][tt] = __builtin_amdgcn_mfma_f32_16x16x32_bf16(kf0, aq[1][0], acc[1][tt], 0, 0, 0);
        acc[1][tt] = __builtin_amdgcn_mfma_f32_16x16x32_bf16(kf1, aq[1][1], acc[1][tt], 0, 0, 0);
    }
    if (!clipped) {
#pragma unroll
        for (int rt = 0; rt < 2; ++rt) {
            const unsigned short* rsrow = &PbB[(size_t)(rt * 16 + l16) * PBB_S];
            const int cb = k0 + kc * 32 - (q0 + rt * 16 + l16) + 512 - rsb;
#pragma unroll
            for (int tt = 0; tt < 2; ++tt)
#pragma unroll
                for (int i = 0; i < 4; ++i)
                    acc[rt][tt][i] += b2f(rsrow[cb + tt * 16 + quad * 4 + i]);
        }
    } else {
#pragma unroll
        for (int rt = 0; rt < 2; ++rt) {
            const unsigned short* rsrow = &PbB[(size_t)(rt * 16 + l16) * PBB_S];
            const int cb = k0 + kc * 32 - (q0 + rt * 16 + l16) + 512;
#pragma unroll
            for (int tt = 0; tt < 2; ++tt)
#pragma unroll
                for (int i = 0; i < 4; ++i) {
                    const int c = cb + tt * 16 + quad * 4 + i;
                    const int r = min(1024, max(0, c));
                    acc[rt][tt][i] += b2f(rsrow[r - rsb]);
                }
        }
    }
    __syncthreads();   // (2) all RS gathers done -> PbB reusable

    // ---- zero-fill PbB ----
    for (int g = tid; g < TQ * (PBB_S / 8); g += 512) {
        int row = g / (PBB_S / 8), j = g - row * (PBB_S / 8);
        *(uint4*)&PbB[row * PBB_S + j * 8] = make_uint4(0u, 0u, 0u, 0u);
    }
    __syncthreads();   // (3)

    // ---- Phase D: mask + exp2(s-6) + dual P store (PbA packed; PbB skewed) ----
#pragma unroll
    for (int rt = 0; rt < 2; ++rt) {
        const int q = q0 + rt * 16 + l16;
        unsigned short* parow = &PbA[(size_t)(rt * 16 + l16) * PBA_S + kc * 32];
        unsigned short* pbrow = &PbB[(size_t)(rt * 16 + l16) * PBB_S];
        const int cbase = k0 + kc * 32 - q + 512;
        const int* mrow = mask + (size_t)b * (SEQ * SEQ) + (size_t)q * SEQ;
#pragma unroll
        for (int tt = 0; tt < 2; ++tt) {
            u16x4 pk;
            if (mfull) {
#pragma unroll
                for (int i = 0; i < 4; ++i)
                    pk[i] = f2bu(EXP2F(acc[rt][tt][i] - PBIAS));
            } else {
#pragma unroll
                for (int i = 0; i < 4; ++i) {
                    const int k = k0 + kc * 32 + tt * 16 + quad * 4 + i;
                    float s = (mrow[k] == 0) ? -1e20f : acc[rt][tt][i];
                    pk[i] = f2bu(EXP2F(s - PBIAS));
                }
            }
            *(u16x4*)(parow + tt * 16 + quad * 4) = pk;
            const int c0 = cbase + tt * 16 + quad * 4;
            if (!clipped) {
#pragma unroll
                for (int i = 0; i < 4; ++i) pbrow[c0 + i - cb0] = pk[i];
            } else {
#pragma unroll
                for (int i = 0; i < 4; ++i) {
                    const int c = c0 + i;
                    if ((unsigned)(c - 1) < 1023u) pbrow[c - cb0] = pk[i];
                }
            }
        }
    }
    __syncthreads();   // (4)

    // ---- Phase F: wave (rt, dq) owns full 256-k quarter; row-sums via
    // mfma(P, ones): accS total / accSI interior; tail = accS - accSI ----
    {
        const int rt = w & 1;
        const int dq = w >> 1;
        floatx4 accA = {0.f, 0.f, 0.f, 0.f};
        floatx4 accB = {0.f, 0.f, 0.f, 0.f};
        floatx4 accS = {0.f, 0.f, 0.f, 0.f};
        floatx4 accSI = {0.f, 0.f, 0.f, 0.f};
        unsigned short ob[8];
#pragma unroll
        for (int j = 0; j < 8; ++j) ob[j] = 0x3F80;   // bf16 1.0
        const bf16x8 onesf = *(bf16x8*)ob;
        const unsigned short* vbase = vtb + ((size_t)bh * 64 + dq * 16 + l16) * SEQ + k0;
        const unsigned short* rbase = relvtb + (size_t)(dq * 16 + l16) * RELV_S;
#pragma unroll
        for (int it = 0; it < 8; ++it) {
            const int co = it * 32 + quad * 8;
            bf16x8 ap = *(const bf16x8*)&PbA[(size_t)(rt * 16 + l16) * PBA_S + co];
            bf16x8 bv = *(const bf16x8*)(vbase + co);
            accA = __builtin_amdgcn_mfma_f32_16x16x32_bf16(ap, bv, accA, 0, 0, 0);
            accS = __builtin_amdgcn_mfma_f32_16x16x32_bf16(ap, onesf, accS, 0, 0, 0);
        }
        const int nksB = ((cmax - cb0) >> 5) + 1;
        for (int ks = 0; ks < nksB; ++ks) {
            const int co = ks * 32 + quad * 8;
            bf16x8 ar = *(const bf16x8*)&PbB[(size_t)(rt * 16 + l16) * PBB_S + co];
            bf16x8 br = *(const bf16x8*)(rbase + cb0 + co);
            accB = __builtin_amdgcn_mfma_f32_16x16x32_bf16(ar, br, accB, 0, 0, 0);
            accSI = __builtin_amdgcn_mfma_f32_16x16x32_bf16(ar, onesf, accSI, 0, 0, 0);
        }
        const float rv0 = b2f(rbase[0]);      // relv[0][d]
        const float rv1 = b2f(rbase[1024]);   // relv[1024][d]
#pragma unroll
        for (int i = 0; i < 4; ++i) {
            const int row = rt * 16 + quad * 4 + i;
            const int q = q0 + row;
            const float tail = accS[i] - accSI[i];
            const float lowS = (q >= k0 + 512) ? tail : 0.f;
            const float highS = (q <= k0 - 257) ? tail : 0.f;
            const int R = bh * SEQ + q;
            float val = accA[i] + accB[i] + lowS * rv0 + highS * rv1;
            Opart[((size_t)R * 4 + quarter) * 64 + dq * 16 + l16] = __float2half(val);
        }
        if (dq == 0 && l16 == 0) {
#pragma unroll
            for (int i = 0; i < 4; ++i) {
                const int row = rt * 16 + quad * 4 + i;
                ms[(size_t)(bh * SEQ + q0 + row) * 4 + quarter] = accS[i];
            }
        }
    }
}

// ---------------------------------------------------------------------------
// Kernel 3: combine the four k-quarters (no-max: plain sums, one divide).
// ---------------------------------------------------------------------------
__global__ __launch_bounds__(256) void sa_combine_kernel(
    const __half* __restrict__ Opart, const float* __restrict__ ms,
    unsigned short* __restrict__ aob) {
    const int tid = threadIdx.x;
    const int R = blockIdx.x * 4 + (tid >> 6);
    const int d = tid & 63;
    float4 dn = *(const float4*)&ms[(size_t)R * 4];
    const float inv = 1.f / (dn.x + dn.y + dn.z + dn.w);
    float val = 0.f;
#pragma unroll
    for (int j = 0; j < 4; ++j)
        val += __half2float(Opart[((size_t)R * 4 + j) * 64 + d]);
    val *= inv;
    const int bh = R >> 10, q = R & 1023, b = bh >> 4, h = bh & 15;
    aob[((size_t)b * SEQ + q) * EMB + h * 64 + d] = f2bu(val);
}

// ---------------------------------------------------------------------------
// Kernel 4: FC MFMA GEMM (unchanged). out = aob @ Wfc_b^T + bfc.
// ---------------------------------------------------------------------------
__global__ __launch_bounds__(256, 2) void sa_fc_kernel(
    const unsigned short* __restrict__ A, const unsigned short* __restrict__ W,
    const float* __restrict__ bias, float* __restrict__ out) {
    const int t = threadIdx.x;
    const int w = t >> 6, lane = t & 63;
    const int quad = lane >> 4, l16 = lane & 15;
    const int mw = blockIdx.x * 64 + (w & 1) * 32;
    const int nw = blockIdx.y * 256 + (w >> 1) * 128;

    floatx4 acc[2][8];
#pragma unroll
    for (int mt = 0; mt < 2; ++mt)
#pragma unroll
        for (int j = 0; j < 8; ++j) acc[mt][j] = floatx4{0.f, 0.f, 0.f, 0.f};
    float bj[8];
#pragma unroll
    for (int j = 0; j < 8; ++j) bj[j] = bias[nw + j * 16 + l16];

    for (int ks = 0; ks < 32; ++ks) {
        const int co = ks * 32 + quad * 8;
        bf16x8 af0 = *(const bf16x8*)(A + (size_t)(mw + l16) * EMB + co);
        bf16x8 af1 = *(const bf16x8*)(A + (size_t)(mw + 16 + l16) * EMB + co);
#pragma unroll
        for (int j = 0; j < 8; ++j) {
            bf16x8 bf = *(const bf16x8*)(W + (size_t)(nw + j * 16 + l16) * EMB + co);
            acc[0][j] = __builtin_amdgcn_mfma_f32_16x16x32_bf16(af0, bf, acc[0][j], 0, 0, 0);
            acc[1][j] = __builtin_amdgcn_mfma_f32_16x16x32_bf16(af1, bf, acc[1][j], 0, 0, 0);
        }
    }
#pragma unroll
    for (int mt = 0; mt < 2; ++mt)
#pragma unroll
        for (int j = 0; j < 8; ++j) {
            const int col = nw + j * 16 + l16;
#pragma unroll
            for (int i = 0; i < 4; ++i) {
                const size_t row = mw + mt * 16 + quad * 4 + i;
                out[row * EMB + col] = acc[mt][j][i] + bj[j];
            }
        }
}

extern "C" void kernel_launch(void* const* d_in, const int* in_sizes, int n_in,
                              void* d_out, int out_size, void* d_ws, size_t ws_size,
                              hipStream_t stream) {
    const float* query = (const float*)d_in[0];
    const float* key = (const float*)d_in[1];
    const float* value = (const float*)d_in[2];
    const int* mask = (const int*)d_in[3];
    const float* Wq = (const float*)d_in[4];
    const float* bq = (const float*)d_in[5];
    const float* Wk = (const float*)d_in[6];
    const float* bk = (const float*)d_in[7];
    const float* Wv = (const float*)d_in[8];
    const float* bv = (const float*)d_in[9];
    const float* Wfc = (const float*)d_in[10];
    const float* bfc = (const float*)d_in[11];
    const float* relk = (const float*)d_in[12];
    const float* relv = (const float*)d_in[13];
    float* out = (float*)d_out;

    char* base = (char*)d_ws;
    const size_t MB = (size_t)1 << 20;
    // aob overlays qb: qb fully consumed by attn before combine writes aob.
    unsigned short* qb = (unsigned short*)(base + 0 * MB);        // 8 MB
    unsigned short* aob = qb;                                     // overlay
    unsigned short* kb = (unsigned short*)(base + 8 * MB);        // 8 MB
    unsigned short* vtb = (unsigned short*)(base + 16 * MB);      // 8 MB
    unsigned short* wfcb = (unsigned short*)(base + 24 * MB);     // 2 MB
    unsigned short* relkb = (unsigned short*)(base + 26 * MB);                 // 133,120 B
    unsigned short* relvtb = (unsigned short*)(base + 26 * MB + 163840);       // 136,192 B
    unsigned* part = (unsigned*)(base + 26 * MB + 327680);                     // 1 KB
    float* ms = (float*)(base + 27 * MB);                                      // 1 MB
    __half* Opart = (__half*)(base + 29 * MB);                                 // 33.5 MB

    sa_projprep_kernel<<<dim3(1024 + PREPY, 3), 256, 0, stream>>>(
        query, key, value, Wq, Wk, Wv, bq, bk, bv,
        Wfc, relk, relv, mask, qb, kb, vtb, wfcb, relkb, relvtb, part);
    sa_attn_kernel<<<64 * 32 * 4, 512, 0, stream>>>(
        qb, kb, vtb, mask, relkb, relvtb, part, Opart, ms);
    sa_combine_kernel<<<(4 * HEADS * SEQ) / 4, 256, 0, stream>>>(Opart, ms, aob);
    sa_fc_kernel<<<dim3(64, 4), 256, 0, stream>>>(aob, wfcb, bfc, out);
}